// Round 1
// baseline (119.927 us; speedup 1.0000x reference)
//
#include <hip/hip_runtime.h>

#define T_ROWS 16384
#define D_COLS 4096
#define QD_DIM 256
#define H_DIM 128
#define NBLK2 16   // D_COLS / 256

// ---------------------------------------------------------------------------
// Pass 1: partial column sums (plain + attention-weighted).
// grid = (D_COLS/1024, nchunk), block = 256 threads, float4 per thread.
// ---------------------------------------------------------------------------
__global__ void __launch_bounds__(256)
pass1_colsums(const float* __restrict__ E_s, const float* __restrict__ att,
              float* __restrict__ s_part, float* __restrict__ c_part,
              int rows_per) {
    const int tid    = threadIdx.x;
    const int colblk = blockIdx.x;            // 0..3
    const int chunk  = blockIdx.y;            // 0..nchunk-1
    const int col4   = colblk * 256 + tid;    // float4 column index, 0..1023

    int r0 = chunk * rows_per;
    int r1 = r0 + rows_per;
    if (r1 > T_ROWS) r1 = T_ROWS;

    const float4* E4 = reinterpret_cast<const float4*>(E_s);
    float4 s = make_float4(0.f, 0.f, 0.f, 0.f);
    float4 c = make_float4(0.f, 0.f, 0.f, 0.f);

    for (int r = r0; r < r1; ++r) {
        const float w  = att[r];                               // uniform -> s_load/broadcast
        const float4 v = E4[(size_t)r * (D_COLS / 4) + col4];  // coalesced 16B/lane
        s.x += v.x;      s.y += v.y;      s.z += v.z;      s.w += v.w;
        c.x += w * v.x;  c.y += w * v.y;  c.z += w * v.z;  c.w += w * v.w;
    }

    const size_t off = (size_t)chunk * (D_COLS / 4) + col4;
    reinterpret_cast<float4*>(s_part)[off] = s;
    reinterpret_cast<float4*>(c_part)[off] = c;
}

// ---------------------------------------------------------------------------
// Pass 2: finish column sums across chunks, square, reduce to partial energies.
// grid = NBLK2 (16), block = 256. Thread d = blk*256+tid owns one column.
// ---------------------------------------------------------------------------
__global__ void __launch_bounds__(256)
pass2_energies(const float* __restrict__ s_part, const float* __restrict__ c_part,
               float* __restrict__ es_part, float* __restrict__ ec_part,
               int nchunk) {
    const int tid = threadIdx.x;
    const int d   = blockIdx.x * 256 + tid;

    float s = 0.f, c = 0.f;
    for (int k = 0; k < nchunk; ++k) {
        s += s_part[(size_t)k * D_COLS + d];   // coalesced across lanes
        c += c_part[(size_t)k * D_COLS + d];
    }
    float es = s * s;
    float ec = c * c;

    // wave64 reduce
    for (int o = 32; o > 0; o >>= 1) {
        es += __shfl_down(es, o);
        ec += __shfl_down(ec, o);
    }
    __shared__ float ses[4], sec[4];
    const int wave = tid >> 6, lane = tid & 63;
    if (lane == 0) { ses[wave] = es; sec[wave] = ec; }
    __syncthreads();
    if (tid == 0) {
        float a = 0.f, b = 0.f;
        for (int i = 0; i < 4; ++i) { a += ses[i]; b += sec[i]; }
        es_part[blockIdx.x] = a;
        ec_part[blockIdx.x] = b;
    }
}

// ---------------------------------------------------------------------------
// Pass 3: final scalars + tiny MLP. 1 block, 256 threads.
// ---------------------------------------------------------------------------
__global__ void __launch_bounds__(256)
pass3_final(const float* __restrict__ es_part, const float* __restrict__ ec_part,
            const float* __restrict__ E_q, const float* __restrict__ W1,
            const float* __restrict__ b1, const float* __restrict__ W2,
            const float* __restrict__ b2, float* __restrict__ out) {
    __shared__ float eq[QD_DIM];
    __shared__ float h[H_DIM];
    __shared__ float red[2];
    const int tid = threadIdx.x;

    if (tid < QD_DIM) eq[tid] = E_q[tid];
    __syncthreads();

    if (tid < H_DIM) {
        float acc = b1[tid];
        const float* w = W1 + (size_t)tid * QD_DIM;
        #pragma unroll 4
        for (int k = 0; k < QD_DIM; ++k) acc += w[k] * eq[k];
        h[tid] = fmaxf(acc, 0.f);
    }
    __syncthreads();

    float p = (tid < H_DIM) ? W2[tid] * h[tid] : 0.f;
    for (int o = 32; o > 0; o >>= 1) p += __shfl_down(p, o);
    if ((tid & 63) == 0 && tid < H_DIM) red[tid >> 6] = p;
    __syncthreads();

    if (tid == 0) {
        float es = 0.f, ec = 0.f;
        for (int i = 0; i < NBLK2; ++i) { es += es_part[i]; ec += ec_part[i]; }
        const float r   = ec / es;
        const float z   = red[0] + red[1] + b2[0];
        const float rth = 1.f / (1.f + expf(-z));
        out[0] = r;
        out[1] = rth;
    }
}

// ---------------------------------------------------------------------------
extern "C" void kernel_launch(void* const* d_in, const int* in_sizes, int n_in,
                              void* d_out, int out_size, void* d_ws, size_t ws_size,
                              hipStream_t stream) {
    const float* E_s = (const float*)d_in[0];
    const float* E_q = (const float*)d_in[1];
    const float* att = (const float*)d_in[2];
    const float* W1  = (const float*)d_in[3];
    const float* b1  = (const float*)d_in[4];
    const float* W2  = (const float*)d_in[5];
    const float* b2  = (const float*)d_in[6];
    float* out = (float*)d_out;
    float* ws  = (float*)d_ws;

    // Size row-chunk count from available workspace: each chunk needs
    // 2 * D_COLS floats (32 KiB). Cap at 128 chunks (4 MiB, 512 blocks).
    const size_t per_chunk = 2 * (size_t)D_COLS * sizeof(float);
    const size_t reserve   = 64 * sizeof(float);  // partial-energy slots
    int nchunk = 1;
    if (ws_size > reserve + per_chunk)
        nchunk = (int)((ws_size - reserve) / per_chunk);
    if (nchunk > 128) nchunk = 128;
    if (nchunk < 1)   nchunk = 1;
    const int rows_per = (T_ROWS + nchunk - 1) / nchunk;

    float* s_part  = ws;
    float* c_part  = ws + (size_t)nchunk * D_COLS;
    float* es_part = ws + 2 * (size_t)nchunk * D_COLS;
    float* ec_part = es_part + NBLK2;

    pass1_colsums<<<dim3(D_COLS / 1024, nchunk), 256, 0, stream>>>(
        E_s, att, s_part, c_part, rows_per);
    pass2_energies<<<NBLK2, 256, 0, stream>>>(s_part, c_part, es_part, ec_part, nchunk);
    pass3_final<<<1, 256, 0, stream>>>(es_part, ec_part, E_q, W1, b1, W2, b2, out);
}

// Round 2
// 80.972 us; speedup vs baseline: 1.4811x; 1.4811x over previous
//
#include <hip/hip_runtime.h>

#define T_ROWS 16384
#define D_COLS 4096
#define D4     (D_COLS / 4)   // 1024 float4 columns
#define QD_DIM 256
#define H_DIM  128
#define NB2    64             // pass-2 blocks (64 columns each)

// ---------------------------------------------------------------------------
// Pass 1: partial column sums (plain + attention-weighted).
// grid = (2, nchunk), block = 256. Each thread owns TWO float4 columns
// (cA = bx*512+tid, cB = cA+256) and processes rows_per rows, unrolled x2:
// 4 independent 16B loads in flight per iteration.
// ---------------------------------------------------------------------------
__global__ void __launch_bounds__(256)
pass1_colsums(const float* __restrict__ E_s, const float* __restrict__ att,
              float* __restrict__ s_part, float* __restrict__ c_part,
              int rows_per) {
    const int tid   = threadIdx.x;
    const int cA    = blockIdx.x * 512 + tid;   // float4 col index
    const int cB    = cA + 256;
    const int chunk = blockIdx.y;

    const int r0 = chunk * rows_per;
    const int r1 = r0 + rows_per;               // rows_per is even (divisor of 16384)

    const float4* E4 = reinterpret_cast<const float4*>(E_s);

    float4 sA = make_float4(0.f, 0.f, 0.f, 0.f), sB = sA;
    float4 wA = sA, wB = sA;

    for (int r = r0; r < r1; r += 2) {
        const size_t b0 = (size_t)r * D4;
        const size_t b1 = b0 + D4;
        // issue all four loads (independent) before consuming
        const float4 a0 = E4[b0 + cA];
        const float4 v0 = E4[b0 + cB];
        const float4 a1 = E4[b1 + cA];
        const float4 v1 = E4[b1 + cB];
        const float w0 = att[r];
        const float w1 = att[r + 1];

        sA.x += a0.x + a1.x; sA.y += a0.y + a1.y; sA.z += a0.z + a1.z; sA.w += a0.w + a1.w;
        sB.x += v0.x + v1.x; sB.y += v0.y + v1.y; sB.z += v0.z + v1.z; sB.w += v0.w + v1.w;
        wA.x += w0 * a0.x + w1 * a1.x; wA.y += w0 * a0.y + w1 * a1.y;
        wA.z += w0 * a0.z + w1 * a1.z; wA.w += w0 * a0.w + w1 * a1.w;
        wB.x += w0 * v0.x + w1 * v1.x; wB.y += w0 * v0.y + w1 * v1.y;
        wB.z += w0 * v0.z + w1 * v1.z; wB.w += w0 * v0.w + w1 * v1.w;
    }

    const size_t off = (size_t)chunk * D4;
    reinterpret_cast<float4*>(s_part)[off + cA] = sA;
    reinterpret_cast<float4*>(s_part)[off + cB] = sB;
    reinterpret_cast<float4*>(c_part)[off + cA] = wA;
    reinterpret_cast<float4*>(c_part)[off + cB] = wB;
}

// ---------------------------------------------------------------------------
// Pass 2: block b owns 64 columns [b*64, b*64+64). 256 threads = 64 cols x
// 4 chunk-slices. Complete column sums -> square -> block partial energy.
// grid = NB2 (64), fully coalesced 256B wave reads of the partial arrays.
// ---------------------------------------------------------------------------
__global__ void __launch_bounds__(256)
pass2_energies(const float* __restrict__ s_part, const float* __restrict__ c_part,
               float* __restrict__ es_part, float* __restrict__ ec_part,
               int nchunk) {
    const int tid   = threadIdx.x;
    const int col   = blockIdx.x * 64 + (tid & 63);
    const int slice = tid >> 6;                 // 0..3

    float s = 0.f, c = 0.f;
    for (int k = slice; k < nchunk; k += 4) {
        s += s_part[(size_t)k * D_COLS + col];
        c += c_part[(size_t)k * D_COLS + col];
    }
    __shared__ float sh_s[4][64];
    __shared__ float sh_c[4][64];
    sh_s[slice][tid & 63] = s;
    sh_c[slice][tid & 63] = c;
    __syncthreads();

    if (tid < 64) {
        float fs = sh_s[0][tid] + sh_s[1][tid] + sh_s[2][tid] + sh_s[3][tid];
        float fc = sh_c[0][tid] + sh_c[1][tid] + sh_c[2][tid] + sh_c[3][tid];
        float es = fs * fs;
        float ec = fc * fc;
        for (int o = 32; o > 0; o >>= 1) {
            es += __shfl_down(es, o);
            ec += __shfl_down(ec, o);
        }
        if (tid == 0) {
            es_part[blockIdx.x] = es;
            ec_part[blockIdx.x] = ec;
        }
    }
}

// ---------------------------------------------------------------------------
// Pass 3: final scalars + tiny MLP. 1 block, 256 threads.
// ---------------------------------------------------------------------------
__global__ void __launch_bounds__(256)
pass3_final(const float* __restrict__ es_part, const float* __restrict__ ec_part,
            const float* __restrict__ E_q, const float* __restrict__ W1,
            const float* __restrict__ b1, const float* __restrict__ W2,
            const float* __restrict__ b2, float* __restrict__ out) {
    __shared__ float eq[QD_DIM];
    __shared__ float h[H_DIM];
    __shared__ float red[2];
    const int tid = threadIdx.x;

    if (tid < QD_DIM) eq[tid] = E_q[tid];
    __syncthreads();

    if (tid < H_DIM) {
        float acc = b1[tid];
        const float* w = W1 + (size_t)tid * QD_DIM;
        #pragma unroll 4
        for (int k = 0; k < QD_DIM; ++k) acc += w[k] * eq[k];
        h[tid] = fmaxf(acc, 0.f);
    }
    __syncthreads();

    float p = (tid < H_DIM) ? W2[tid] * h[tid] : 0.f;
    for (int o = 32; o > 0; o >>= 1) p += __shfl_down(p, o);
    if ((tid & 63) == 0 && tid < H_DIM) red[tid >> 6] = p;
    __syncthreads();

    if (tid == 0) {
        float es = 0.f, ec = 0.f;
        for (int i = 0; i < NB2; ++i) { es += es_part[i]; ec += ec_part[i]; }
        const float r   = ec / es;
        const float z   = red[0] + red[1] + b2[0];
        const float rth = 1.f / (1.f + expf(-z));
        out[0] = r;
        out[1] = rth;
    }
}

// ---------------------------------------------------------------------------
extern "C" void kernel_launch(void* const* d_in, const int* in_sizes, int n_in,
                              void* d_out, int out_size, void* d_ws, size_t ws_size,
                              hipStream_t stream) {
    const float* E_s = (const float*)d_in[0];
    const float* E_q = (const float*)d_in[1];
    const float* att = (const float*)d_in[2];
    const float* W1  = (const float*)d_in[3];
    const float* b1  = (const float*)d_in[4];
    const float* W2  = (const float*)d_in[5];
    const float* b2  = (const float*)d_in[6];
    float* out = (float*)d_out;
    float* ws  = (float*)d_ws;

    // Pick the largest power-of-two chunk count (<=256) whose partials fit in
    // d_ws; all candidates divide 16384 so rows_per is exact and even.
    const size_t reserve = 2 * NB2 * sizeof(float);
    int nchunk = 256;
    while (nchunk > 1 &&
           2 * (size_t)nchunk * D_COLS * sizeof(float) + reserve > ws_size)
        nchunk >>= 1;
    const int rows_per = T_ROWS / nchunk;

    float* s_part  = ws;
    float* c_part  = ws + (size_t)nchunk * D_COLS;
    float* es_part = ws + 2 * (size_t)nchunk * D_COLS;
    float* ec_part = es_part + NB2;

    pass1_colsums<<<dim3(2, nchunk), 256, 0, stream>>>(E_s, att, s_part, c_part, rows_per);
    pass2_energies<<<NB2, 256, 0, stream>>>(s_part, c_part, es_part, ec_part, nchunk);
    pass3_final<<<1, 256, 0, stream>>>(es_part, ec_part, E_q, W1, b1, W2, b2, out);
}

// Round 3
// 72.903 us; speedup vs baseline: 1.6450x; 1.1107x over previous
//
#include <hip/hip_runtime.h>

#define T_ROWS   16384
#define D_COLS   4096
#define D4       1024          // float4 columns
#define QD_DIM   256
#define H_DIM    128
#define NCHUNK   256
#define ROWS_PER 64            // T_ROWS / NCHUNK
#define NB2      256           // pass-2 blocks (16 cols each)

// ---------------------------------------------------------------------------
// Pass 1: partial column sums (plain + weighted). grid (4, NCHUNK), 256 thr.
// One float4 column per thread, 64 rows, 8 loads in flight per batch.
// Also zeroes the pass-2 completion counter (block (0,0)).
// ---------------------------------------------------------------------------
__global__ void __launch_bounds__(256, 4)
pass1_colsums(const float* __restrict__ E_s, const float* __restrict__ att,
              float* __restrict__ s_part, float* __restrict__ c_part,
              int* __restrict__ counter) {
    const int tid   = threadIdx.x;
    const int c4    = blockIdx.x * 256 + tid;   // 0..1023
    const int chunk = blockIdx.y;               // 0..255
    if (c4 == 0 && chunk == 0) *counter = 0;

    const int r0 = chunk * ROWS_PER;
    __shared__ float watt[ROWS_PER];
    if (tid < ROWS_PER) watt[tid] = att[r0 + tid];
    __syncthreads();

    const float4* p = reinterpret_cast<const float4*>(E_s) + (size_t)r0 * D4 + c4;
    float4 s = make_float4(0.f, 0.f, 0.f, 0.f);
    float4 c = make_float4(0.f, 0.f, 0.f, 0.f);

    #pragma unroll
    for (int i = 0; i < ROWS_PER / 8; ++i) {
        float4 v[8];
        #pragma unroll
        for (int j = 0; j < 8; ++j)
            v[j] = p[(size_t)(i * 8 + j) * D4];      // 8 independent 16B loads
        #pragma unroll
        for (int j = 0; j < 8; ++j) {
            const float w = watt[i * 8 + j];
            s.x += v[j].x; s.y += v[j].y; s.z += v[j].z; s.w += v[j].w;
            c.x = fmaf(w, v[j].x, c.x); c.y = fmaf(w, v[j].y, c.y);
            c.z = fmaf(w, v[j].z, c.z); c.w = fmaf(w, v[j].w, c.w);
        }
    }

    const size_t off = (size_t)chunk * D4 + c4;
    reinterpret_cast<float4*>(s_part)[off] = s;
    reinterpret_cast<float4*>(c_part)[off] = c;
}

// ---------------------------------------------------------------------------
// Pass 2 + final: block b owns 16 columns; 16 chunk-slices per block.
// Last block to finish (atomic counter) reduces the 256 block partials and
// runs the tiny MLP, writing out[0..1].
// ---------------------------------------------------------------------------
__global__ void __launch_bounds__(256)
pass2_final(const float* __restrict__ s_part, const float* __restrict__ c_part,
            const float* __restrict__ E_q, const float* __restrict__ W1,
            const float* __restrict__ b1, const float* __restrict__ W2,
            const float* __restrict__ b2, float* __restrict__ es_part,
            float* __restrict__ ec_part, int* __restrict__ counter,
            float* __restrict__ out) {
    const int tid   = threadIdx.x;
    const int col   = blockIdx.x * 16 + (tid & 15);
    const int slice = tid >> 4;                   // 0..15

    float s = 0.f, c = 0.f;
    #pragma unroll 8
    for (int k = slice; k < NCHUNK; k += 16) {
        s += s_part[(size_t)k * D_COLS + col];
        c += c_part[(size_t)k * D_COLS + col];
    }
    __shared__ float sh_s[16][17];
    __shared__ float sh_c[16][17];
    sh_s[slice][tid & 15] = s;
    sh_c[slice][tid & 15] = c;
    __syncthreads();

    float es = 0.f, ec = 0.f;
    if (tid < 16) {
        float fs = 0.f, fc = 0.f;
        #pragma unroll
        for (int q = 0; q < 16; ++q) { fs += sh_s[q][tid]; fc += sh_c[q][tid]; }
        es = fs * fs;
        ec = fc * fc;
    }
    // full-wave reduce (lanes >=16 contribute 0; es/ec defined for all lanes)
    #pragma unroll
    for (int o = 32; o > 0; o >>= 1) {
        es += __shfl_down(es, o);
        ec += __shfl_down(ec, o);
    }

    __shared__ int lastflag;
    if (tid == 0) {
        es_part[blockIdx.x] = es;
        ec_part[blockIdx.x] = ec;
        __threadfence();                          // release partials
        const int old = atomicAdd(counter, 1);
        lastflag = (old == NB2 - 1);
    }
    __syncthreads();
    if (!lastflag) return;

    // ---- last block: final reduction + MLP ----
    __threadfence();                              // acquire
    float fes = atomicAdd(&es_part[tid], 0.f);    // coherent read-back
    float fec = atomicAdd(&ec_part[tid], 0.f);
    #pragma unroll
    for (int o = 32; o > 0; o >>= 1) {
        fes += __shfl_down(fes, o);
        fec += __shfl_down(fec, o);
    }
    __shared__ float r_es[4], r_ec[4];
    if ((tid & 63) == 0) { r_es[tid >> 6] = fes; r_ec[tid >> 6] = fec; }

    __shared__ float eq[QD_DIM];
    eq[tid] = E_q[tid];
    __syncthreads();

    __shared__ float hsh[H_DIM];
    if (tid < H_DIM) {
        float a = b1[tid];
        const float* w = W1 + (size_t)tid * QD_DIM;
        #pragma unroll 8
        for (int k = 0; k < QD_DIM; ++k) a = fmaf(w[k], eq[k], a);
        hsh[tid] = fmaxf(a, 0.f);
    }
    __syncthreads();

    float pk = (tid < H_DIM) ? W2[tid] * hsh[tid] : 0.f;
    #pragma unroll
    for (int o = 32; o > 0; o >>= 1) pk += __shfl_down(pk, o);
    __shared__ float red[4];
    if ((tid & 63) == 0) red[tid >> 6] = pk;
    __syncthreads();

    if (tid == 0) {
        const float es_t = r_es[0] + r_es[1] + r_es[2] + r_es[3];
        const float ec_t = r_ec[0] + r_ec[1] + r_ec[2] + r_ec[3];
        const float z    = red[0] + red[1] + red[2] + red[3] + b2[0];
        out[0] = ec_t / es_t;
        out[1] = 1.f / (1.f + expf(-z));
    }
}

// ---------------------------------------------------------------------------
extern "C" void kernel_launch(void* const* d_in, const int* in_sizes, int n_in,
                              void* d_out, int out_size, void* d_ws, size_t ws_size,
                              hipStream_t stream) {
    const float* E_s = (const float*)d_in[0];
    const float* E_q = (const float*)d_in[1];
    const float* att = (const float*)d_in[2];
    const float* W1  = (const float*)d_in[3];
    const float* b1  = (const float*)d_in[4];
    const float* W2  = (const float*)d_in[5];
    const float* b2  = (const float*)d_in[6];
    float* out = (float*)d_out;
    float* ws  = (float*)d_ws;

    // ws layout: s_part | c_part | es_part | ec_part | counter  (~8.4 MB; ws is 1 GB)
    float* s_part  = ws;
    float* c_part  = s_part + (size_t)NCHUNK * D_COLS;
    float* es_part = c_part + (size_t)NCHUNK * D_COLS;
    float* ec_part = es_part + NB2;
    int*   counter = (int*)(ec_part + NB2);

    pass1_colsums<<<dim3(4, NCHUNK), 256, 0, stream>>>(E_s, att, s_part, c_part, counter);
    pass2_final<<<NB2, 256, 0, stream>>>(s_part, c_part, E_q, W1, b1, W2, b2,
                                         es_part, ec_part, counter, out);
}

// Round 5
// 62.914 us; speedup vs baseline: 1.9062x; 1.1588x over previous
//
#include <hip/hip_runtime.h>

#define T_ROWS   16384
#define D_COLS   4096
#define D4       1024          // float4 columns
#define QD_DIM   256
#define H_DIM    128
#define NCHUNK   256
#define ROWS_PER 64            // T_ROWS / NCHUNK
#define NB2      256           // pass-2 blocks (16 cols each)

typedef float vf4 __attribute__((ext_vector_type(4)));  // native vector for nontemporal builtins

// ---------------------------------------------------------------------------
// Pass 1: partial column sums (plain + weighted). grid (4, NCHUNK+1), 256 thr.
// Blocks with chunk < NCHUNK stream E_s (nontemporal, 8 loads in flight).
// The single extra block (chunk==NCHUNK, bx==0) computes the threshold MLP
// concurrently (it has no dependence on E_s) and writes out[1].
// ---------------------------------------------------------------------------
__global__ void __launch_bounds__(256, 4)
pass1_colsums(const float* __restrict__ E_s, const float* __restrict__ att,
              const float* __restrict__ E_q, const float* __restrict__ W1,
              const float* __restrict__ b1, const float* __restrict__ W2,
              const float* __restrict__ b2,
              float* __restrict__ s_part, float* __restrict__ c_part,
              int* __restrict__ counter, float* __restrict__ out) {
    const int tid   = threadIdx.x;
    const int chunk = blockIdx.y;               // 0..NCHUNK

    if (chunk == NCHUNK) {
        // ---- threshold MLP block (runs under the shadow of the streaming) ----
        if (blockIdx.x != 0) return;
        __shared__ float eq[QD_DIM];
        eq[tid] = E_q[tid];
        __syncthreads();

        const int row  = tid >> 1;              // 0..127
        const int half = tid & 1;               // 0..1
        const float4* w4 = reinterpret_cast<const float4*>(W1 + (size_t)row * QD_DIM)
                           + half * 32;
        const float4* e4 = reinterpret_cast<const float4*>(eq) + half * 32;
        float acc = 0.f;
        #pragma unroll 8
        for (int k = 0; k < 32; ++k) {
            const float4 w = w4[k];
            const float4 e = e4[k];
            acc = fmaf(w.x, e.x, fmaf(w.y, e.y, fmaf(w.z, e.z, fmaf(w.w, e.w, acc))));
        }
        acc += __shfl_xor(acc, 1);              // combine the two halves
        const float h = fmaxf(acc + b1[row], 0.f);
        float p = half ? 0.f : W2[row] * h;
        #pragma unroll
        for (int o = 32; o > 0; o >>= 1) p += __shfl_down(p, o);
        __shared__ float red[4];
        if ((tid & 63) == 0) red[tid >> 6] = p;
        __syncthreads();
        if (tid == 0) {
            const float z = red[0] + red[1] + red[2] + red[3] + b2[0];
            out[1] = 1.f / (1.f + expf(-z));
        }
        return;
    }

    const int c4 = blockIdx.x * 256 + tid;      // float4 column, 0..1023
    if (c4 == 0 && chunk == 0) *counter = 0;

    const int r0 = chunk * ROWS_PER;
    __shared__ float watt[ROWS_PER];
    if (tid < ROWS_PER) watt[tid] = att[r0 + tid];
    __syncthreads();

    const vf4* p = reinterpret_cast<const vf4*>(E_s) + (size_t)r0 * D4 + c4;
    float sx = 0.f, sy = 0.f, sz = 0.f, sw = 0.f;
    float cx = 0.f, cy = 0.f, cz = 0.f, cw = 0.f;

    #pragma unroll
    for (int i = 0; i < ROWS_PER / 8; ++i) {
        vf4 v[8];
        #pragma unroll
        for (int j = 0; j < 8; ++j)
            v[j] = __builtin_nontemporal_load(&p[(size_t)(i * 8 + j) * D4]);
        #pragma unroll
        for (int j = 0; j < 8; ++j) {
            const float w = watt[i * 8 + j];
            sx += v[j].x; sy += v[j].y; sz += v[j].z; sw += v[j].w;
            cx = fmaf(w, v[j].x, cx); cy = fmaf(w, v[j].y, cy);
            cz = fmaf(w, v[j].z, cz); cw = fmaf(w, v[j].w, cw);
        }
    }

    const size_t off = (size_t)chunk * D4 + c4;
    vf4 s; s.x = sx; s.y = sy; s.z = sz; s.w = sw;
    vf4 c; c.x = cx; c.y = cy; c.z = cz; c.w = cw;
    reinterpret_cast<vf4*>(s_part)[off] = s;
    reinterpret_cast<vf4*>(c_part)[off] = c;
}

// ---------------------------------------------------------------------------
// Pass 2 + final energies. Block b owns 16 columns (4 float4 cols); threads =
// 4 col4 x 64 chunk-slices; float4 loads (8 in flight). LDS tree-reduce over
// slices, square, block partial; last block reduces 256 partials -> out[0].
// ---------------------------------------------------------------------------
__global__ void __launch_bounds__(256)
pass2_final(const float* __restrict__ s_part, const float* __restrict__ c_part,
            float* __restrict__ es_part, float* __restrict__ ec_part,
            int* __restrict__ counter, float* __restrict__ out) {
    const int tid   = threadIdx.x;
    const int l     = tid & 3;                  // float4-col within block
    const int slice = tid >> 2;                 // 0..63
    const int c4    = blockIdx.x * 4 + l;       // global float4 col

    const float4* s4  = reinterpret_cast<const float4*>(s_part);
    const float4* c4p = reinterpret_cast<const float4*>(c_part);

    float4 sA = make_float4(0.f, 0.f, 0.f, 0.f);
    float4 cA = sA;
    #pragma unroll
    for (int k = slice; k < NCHUNK; k += 64) {
        const float4 a = s4[(size_t)k * D4 + c4];
        const float4 b = c4p[(size_t)k * D4 + c4];
        sA.x += a.x; sA.y += a.y; sA.z += a.z; sA.w += a.w;
        cA.x += b.x; cA.y += b.y; cA.z += b.z; cA.w += b.w;
    }

    __shared__ float4 shs[64][4];
    __shared__ float4 shc[64][4];
    shs[slice][l] = sA;
    shc[slice][l] = cA;
    __syncthreads();

    #pragma unroll
    for (int st = 32; st > 0; st >>= 1) {
        if (slice < st) {
            float4 a = shs[slice][l], b = shs[slice + st][l];
            a.x += b.x; a.y += b.y; a.z += b.z; a.w += b.w;
            shs[slice][l] = a;
            float4 u = shc[slice][l], v = shc[slice + st][l];
            u.x += v.x; u.y += v.y; u.z += v.z; u.w += v.w;
            shc[slice][l] = u;
        }
        __syncthreads();
    }

    float es = 0.f, ec = 0.f;
    if (tid < 4) {
        const float4 fs = shs[0][tid];
        const float4 fc = shc[0][tid];
        es = fs.x * fs.x + fs.y * fs.y + fs.z * fs.z + fs.w * fs.w;
        ec = fc.x * fc.x + fc.y * fc.y + fc.z * fc.z + fc.w * fc.w;
    }
    #pragma unroll
    for (int o = 32; o > 0; o >>= 1) {
        es += __shfl_down(es, o);
        ec += __shfl_down(ec, o);
    }

    __shared__ int lastflag;
    if (tid == 0) {
        es_part[blockIdx.x] = es;
        ec_part[blockIdx.x] = ec;
        __threadfence();                        // release partials
        lastflag = (atomicAdd(counter, 1) == NB2 - 1);
    }
    __syncthreads();
    if (!lastflag) return;

    // ---- last block: reduce 256 partials, write r ----
    __threadfence();                            // acquire
    float fes = atomicAdd(&es_part[tid], 0.f);  // coherent read-back
    float fec = atomicAdd(&ec_part[tid], 0.f);
    #pragma unroll
    for (int o = 32; o > 0; o >>= 1) {
        fes += __shfl_down(fes, o);
        fec += __shfl_down(fec, o);
    }
    __shared__ float r_es[4], r_ec[4];
    if ((tid & 63) == 0) { r_es[tid >> 6] = fes; r_ec[tid >> 6] = fec; }
    __syncthreads();
    if (tid == 0) {
        const float es_t = r_es[0] + r_es[1] + r_es[2] + r_es[3];
        const float ec_t = r_ec[0] + r_ec[1] + r_ec[2] + r_ec[3];
        out[0] = ec_t / es_t;
    }
}

// ---------------------------------------------------------------------------
extern "C" void kernel_launch(void* const* d_in, const int* in_sizes, int n_in,
                              void* d_out, int out_size, void* d_ws, size_t ws_size,
                              hipStream_t stream) {
    const float* E_s = (const float*)d_in[0];
    const float* E_q = (const float*)d_in[1];
    const float* att = (const float*)d_in[2];
    const float* W1  = (const float*)d_in[3];
    const float* b1  = (const float*)d_in[4];
    const float* W2  = (const float*)d_in[5];
    const float* b2  = (const float*)d_in[6];
    float* out = (float*)d_out;
    float* ws  = (float*)d_ws;

    // ws layout: s_part | c_part | es_part | ec_part | counter  (~8.4 MB)
    float* s_part  = ws;
    float* c_part  = s_part + (size_t)NCHUNK * D_COLS;
    float* es_part = c_part + (size_t)NCHUNK * D_COLS;
    float* ec_part = es_part + NB2;
    int*   counter = (int*)(ec_part + NB2);

    pass1_colsums<<<dim3(4, NCHUNK + 1), 256, 0, stream>>>(
        E_s, att, E_q, W1, b1, W2, b2, s_part, c_part, counter, out);
    pass2_final<<<NB2, 256, 0, stream>>>(s_part, c_part, es_part, ec_part, counter, out);
}